// Round 2
// baseline (1362.938 us; speedup 1.0000x reference)
//
#include <hip/hip_runtime.h>
#include <math.h>

#define Hdim 512
#define Bdim 32
#define Sdim 2048
#define Kdim 1024   // 2*H

#define MT 16       // rows per block in scores kernel
#define KT 16       // k-tile

// ---------------- Kernel 1: dec_proj = decoder_hide @ W_h + b_attn ----------
__global__ __launch_bounds__(256) void dec_proj_kernel(
    const float* __restrict__ dec, const float* __restrict__ W_attn,
    const float* __restrict__ b_attn, float* __restrict__ dec_proj)
{
    __shared__ float drow[Hdim];
    const int b = blockIdx.x;
    const int t = threadIdx.x;
    for (int i = t; i < Hdim; i += 256) drow[i] = dec[b * Hdim + i];
    __syncthreads();
    for (int h = t; h < Hdim; h += 256) {
        float acc = b_attn[h];
        #pragma unroll 8
        for (int k = 0; k < Hdim; ++k)
            acc = fmaf(drow[k], W_attn[k * Hdim + h], acc);
        dec_proj[b * Hdim + h] = acc;
    }
}

// ---------------- fast tanh (accurate to ~1e-7, branch-free) ----------------
__device__ __forceinline__ float fast_tanh(float x) {
    float ax = fabsf(x);
    float e  = __expf(-2.0f * ax);
    float r  = (1.0f - e) / (1.0f + e);
    return copysignf(r, x);
}

// ---------------- Kernel 2: fused scores ------------------------------------
// scores[row] = sum_h v_w[h] * tanh( (enc[row,:] @ W_e)[h] + dec_proj[b][h] )
#define FMA2(a, r) { acc0[r] = fmaf((a), bv0, acc0[r]); acc1[r] = fmaf((a), bv1, acc1[r]); }

__global__ __launch_bounds__(256) void scores_kernel(
    const float* __restrict__ enc,      // [B*S][1024]
    const float* __restrict__ W_attn,   // W_e = W_attn + H*H, [1024][512]
    const float* __restrict__ dec_proj, // [B][512]
    const float* __restrict__ v_w,      // [512]
    float* __restrict__ scores)         // [B*S]
{
    const float* We = W_attn + Hdim * Hdim;
    __shared__ float b_lds[KT * Hdim];   // 32 KB, [k][c]
    __shared__ float a_lds[KT * MT];     // 1 KB,  [k][r]
    __shared__ float red[4][MT];

    const int t    = threadIdx.x;
    const int row0 = blockIdx.x * MT;
    const int c0   = t;
    const int c1   = t + 256;
    const int b    = row0 / Sdim;        // all MT rows share one batch index

    float acc0[MT], acc1[MT];
    #pragma unroll
    for (int r = 0; r < MT; ++r) { acc0[r] = 0.0f; acc1[r] = 0.0f; }

    const int ar = t >> 4;      // 0..15 row for A staging
    const int ak = t & 15;      // 0..15 k   for A staging

    for (int kt = 0; kt < Kdim; kt += KT) {
        __syncthreads();  // previous tile's reads complete before overwrite
        // stage A tile: 16 rows x 16 k (coalesced 64B runs per row)
        a_lds[ak * MT + ar] = enc[(row0 + ar) * Kdim + kt + ak];
        // stage B tile: 16 k x 512 cols = 2048 float4, 8 per thread, coalesced
        {
            const float4* gsrc = reinterpret_cast<const float4*>(We + kt * Hdim);
            float4* ldst = reinterpret_cast<float4*>(b_lds);
            #pragma unroll
            for (int j = 0; j < 8; ++j)
                ldst[j * 256 + t] = gsrc[j * 256 + t];
        }
        __syncthreads();

        #pragma unroll
        for (int k = 0; k < KT; ++k) {
            float bv0 = b_lds[k * Hdim + c0];   // stride-1: 2-way (free)
            float bv1 = b_lds[k * Hdim + c1];
            const float4* a4 = reinterpret_cast<const float4*>(a_lds + k * MT);
            float4 A0 = a4[0], A1 = a4[1], A2 = a4[2], A3 = a4[3]; // broadcast
            FMA2(A0.x, 0)  FMA2(A0.y, 1)  FMA2(A0.z, 2)  FMA2(A0.w, 3)
            FMA2(A1.x, 4)  FMA2(A1.y, 5)  FMA2(A1.z, 6)  FMA2(A1.w, 7)
            FMA2(A2.x, 8)  FMA2(A2.y, 9)  FMA2(A2.z,10)  FMA2(A2.w,11)
            FMA2(A3.x,12)  FMA2(A3.y,13)  FMA2(A3.z,14)  FMA2(A3.w,15)
        }
    }

    // Epilogue: + dec_proj, tanh, * v_w, reduce over 512 cols per row
    const float dp0 = dec_proj[b * Hdim + c0];
    const float dp1 = dec_proj[b * Hdim + c1];
    const float vw0 = v_w[c0];
    const float vw1 = v_w[c1];

    float p[MT];
    #pragma unroll
    for (int r = 0; r < MT; ++r)
        p[r] = vw0 * fast_tanh(acc0[r] + dp0) + vw1 * fast_tanh(acc1[r] + dp1);

    const int lane = t & 63;
    const int wid  = t >> 6;
    #pragma unroll
    for (int r = 0; r < MT; ++r) {
        float v = p[r];
        v += __shfl_down(v, 32, 64);
        v += __shfl_down(v, 16, 64);
        v += __shfl_down(v,  8, 64);
        v += __shfl_down(v,  4, 64);
        v += __shfl_down(v,  2, 64);
        v += __shfl_down(v,  1, 64);
        if (lane == 0) red[wid][r] = v;
    }
    __syncthreads();
    if (t < MT)
        scores[row0 + t] = red[0][t] + red[1][t] + red[2][t] + red[3][t];
}

// ---------------- Kernel 3: masked softmax over S per batch -----------------
__global__ __launch_bounds__(256) void softmax_kernel(
    const float* __restrict__ scores, const int* __restrict__ mask,
    float* __restrict__ out)
{
    __shared__ float sred[8];
    const int b = blockIdx.x;
    const int t = threadIdx.x;
    const int lane = t & 63;
    const int wid  = t >> 6;

    float x[8];
    float m = -1e30f;
    #pragma unroll
    for (int j = 0; j < 8; ++j) {
        int idx = b * Sdim + j * 256 + t;
        float v = scores[idx];
        if (mask[idx] == 0) v = -100000.0f;
        x[j] = v;
        m = fmaxf(m, v);
    }
    #pragma unroll
    for (int off = 32; off >= 1; off >>= 1)
        m = fmaxf(m, __shfl_xor(m, off, 64));
    if (lane == 0) sred[wid] = m;
    __syncthreads();
    m = fmaxf(fmaxf(sred[0], sred[1]), fmaxf(sred[2], sred[3]));

    float s = 0.0f;
    #pragma unroll
    for (int j = 0; j < 8; ++j) {
        float e = __expf(x[j] - m);
        x[j] = e;
        s += e;
    }
    #pragma unroll
    for (int off = 32; off >= 1; off >>= 1)
        s += __shfl_xor(s, off, 64);
    if (lane == 0) sred[4 + wid] = s;
    __syncthreads();
    s = sred[4] + sred[5] + sred[6] + sred[7];

    const float inv = 1.0f / s;
    #pragma unroll
    for (int j = 0; j < 8; ++j)
        out[b * Sdim + j * 256 + t] = x[j] * inv;
}

// ---------------- launch ----------------------------------------------------
extern "C" void kernel_launch(void* const* d_in, const int* in_sizes, int n_in,
                              void* d_out, int out_size, void* d_ws, size_t ws_size,
                              hipStream_t stream) {
    const float* dec  = (const float*)d_in[0];   // (B, H)
    const float* enc  = (const float*)d_in[1];   // (B, S, 2H)
    const int*   mask = (const int*)  d_in[2];   // (B, S)
    const float* W    = (const float*)d_in[3];   // (3H, H)
    const float* ba   = (const float*)d_in[4];   // (H,)
    const float* vw   = (const float*)d_in[5];   // (H,)
    float* out = (float*)d_out;                  // (B, S)

    float* dec_proj = (float*)d_ws;              // B*H floats
    float* scores   = dec_proj + Bdim * Hdim;    // B*S floats

    dec_proj_kernel<<<Bdim, 256, 0, stream>>>(dec, W, ba, dec_proj);
    scores_kernel<<<(Bdim * Sdim) / MT, 256, 0, stream>>>(enc, W, dec_proj, vw, scores);
    softmax_kernel<<<Bdim, 256, 0, stream>>>(scores, mask, out);
}

// Round 3
// 486.259 us; speedup vs baseline: 2.8029x; 2.8029x over previous
//
#include <hip/hip_runtime.h>
#include <math.h>

#define Hdim 512
#define Bdim 32
#define Sdim 2048
#define Kdim 1024    // 2*H
#define Mtot (Bdim * Sdim)   // 65536 rows

// scores GEMM tiling
#define BM 128
#define BN 128
#define BK 32
#define AST 40       // LDS row stride (elements) for A/B tiles: 80B, 16B-aligned, breaks pow2 banks

typedef __attribute__((ext_vector_type(8))) short short8;
typedef __attribute__((ext_vector_type(4))) float floatx4;

// ---------------- fp32 -> bf16 (RNE) ----------------------------------------
__device__ __forceinline__ short f2bf(float f) {
    union { float f; unsigned u; } v; v.f = f;
    unsigned r = v.u + 0x7fffu + ((v.u >> 16) & 1u);
    return (short)(r >> 16);
}

__device__ __forceinline__ float fast_tanh(float x) {
    float ax = fabsf(x);
    float e  = __expf(-2.0f * ax);
    float r  = (1.0f - e) / (1.0f + e);
    return copysignf(r, x);
}

// ---------------- Kernel 0: W_e fp32 [k][n] -> bf16 [n][k] (transpose) ------
__global__ __launch_bounds__(256) void conv_W_kernel(
    const float* __restrict__ W_attn, short* __restrict__ Wb)
{
    const float* We = W_attn + Hdim * Hdim;   // [1024][512]
    __shared__ short tile[32][33];
    const int k0 = (blockIdx.x >> 4) * 32;    // 32 k-blocks
    const int n0 = (blockIdx.x & 15) * 32;    // 16 n-blocks
    const int r = threadIdx.x >> 5, c = threadIdx.x & 31;
    #pragma unroll
    for (int rr = 0; rr < 4; ++rr)
        tile[r + rr * 8][c] = f2bf(We[(size_t)(k0 + r + rr * 8) * Hdim + n0 + c]);
    __syncthreads();
    #pragma unroll
    for (int rr = 0; rr < 4; ++rr)
        Wb[(size_t)(n0 + r + rr * 8) * Kdim + k0 + c] = tile[c][r + rr * 8];
}

// ---------------- Kernel 1: dec_proj = decoder_hide @ W_h + b_attn ----------
__global__ __launch_bounds__(256) void dec_proj_kernel(
    const float* __restrict__ dec, const float* __restrict__ W_attn,
    const float* __restrict__ b_attn, float* __restrict__ dec_proj)
{
    __shared__ float part[2][128];
    const int b  = blockIdx.x;
    const int cb = blockIdx.y;
    const int t  = threadIdx.x;
    const int c  = cb * 128 + (t & 127);
    const int kh = t >> 7;               // 0/1 -> k halves
    float acc = 0.0f;
    const int kbeg = kh * 256, kend = kbeg + 256;
    #pragma unroll 8
    for (int k = kbeg; k < kend; ++k)
        acc = fmaf(dec[b * Hdim + k], W_attn[(size_t)k * Hdim + c], acc);
    part[kh][t & 127] = acc;
    __syncthreads();
    if (t < 128)
        dec_proj[b * Hdim + cb * 128 + t] = part[0][t] + part[1][t] + b_attn[cb * 128 + t];
}

// ---------------- Kernel 2: fused MFMA scores -------------------------------
// partial[nblk][row] = sum_{h in nblk's 128 cols} v_w[h]*tanh(enc_proj[row][h]+dec_proj[b][h])
__global__ __launch_bounds__(256, 3) void scores_kernel(
    const float* __restrict__ enc,      // [65536][1024] fp32
    const short* __restrict__ Wb,       // [512][1024] bf16 (n-major, k contiguous)
    const float* __restrict__ dec_proj, // [32][512]
    const float* __restrict__ v_w,      // [512]
    float* __restrict__ part)           // [4][65536]
{
    __shared__ __align__(16) short Asm[BM * AST];  // [m][k] bf16, 10 KB
    __shared__ __align__(16) short Bsm[BN * AST];  // [n][k] bf16, 10 KB
    __shared__ float redl[BM][2];                  // 1 KB

    const int t    = threadIdx.x;
    const int nblk = blockIdx.x & 3;
    const int mblk = blockIdx.x >> 2;
    const int row0 = mblk * BM;
    const int n0   = nblk * BN;
    const int b    = row0 / Sdim;        // 16 m-blocks per batch -> uniform

    const int w    = t >> 6;             // wave 0..3
    const int lane = t & 63;
    const int ln   = lane & 15;
    const int quad = lane >> 4;
    const int wr   = (w >> 1) * 64;      // wave row offset in tile
    const int wc   = (w & 1) * 64;       // wave col offset in tile

    // staging map: thread -> (row-or-n = t>>1, k-half = (t&1)*16)
    const int sm = t >> 1;
    const int sk = (t & 1) * 16;

    floatx4 acc[4][4];
    #pragma unroll
    for (int i = 0; i < 4; ++i)
        #pragma unroll
        for (int j = 0; j < 4; ++j)
            acc[i][j] = (floatx4)(0.0f);

    const float* Ag = enc + (size_t)(row0 + sm) * Kdim + sk;
    const short* Bg = Wb + (size_t)(n0 + sm) * Kdim + sk;

    for (int kt = 0; kt < Kdim; kt += BK) {
        __syncthreads();   // previous tile's frag reads complete
        // ---- stage A: 128x32 fp32 -> bf16, padded rows ----
        {
            const floatx4* g = (const floatx4*)(Ag + kt);
            floatx4 f0 = g[0], f1 = g[1], f2 = g[2], f3 = g[3];
            short8 lo, hi;
            lo[0]=f2bf(f0.x); lo[1]=f2bf(f0.y); lo[2]=f2bf(f0.z); lo[3]=f2bf(f0.w);
            lo[4]=f2bf(f1.x); lo[5]=f2bf(f1.y); lo[6]=f2bf(f1.z); lo[7]=f2bf(f1.w);
            hi[0]=f2bf(f2.x); hi[1]=f2bf(f2.y); hi[2]=f2bf(f2.z); hi[3]=f2bf(f2.w);
            hi[4]=f2bf(f3.x); hi[5]=f2bf(f3.y); hi[6]=f2bf(f3.z); hi[7]=f2bf(f3.w);
            *(short8*)&Asm[sm * AST + sk]     = lo;
            *(short8*)&Asm[sm * AST + sk + 8] = hi;
        }
        // ---- stage B: 128x32 bf16 (already converted) ----
        {
            const short8* g = (const short8*)(Bg + kt);
            *(short8*)&Bsm[sm * AST + sk]     = g[0];
            *(short8*)&Bsm[sm * AST + sk + 8] = g[1];
        }
        __syncthreads();

        // ---- fragments + MFMA: wave computes 64x64 via 4x4 of 16x16x32 ----
        short8 af[4], bf[4];
        #pragma unroll
        for (int i = 0; i < 4; ++i)
            af[i] = *(const short8*)&Asm[(wr + i * 16 + ln) * AST + quad * 8];
        #pragma unroll
        for (int j = 0; j < 4; ++j)
            bf[j] = *(const short8*)&Bsm[(wc + j * 16 + ln) * AST + quad * 8];
        #pragma unroll
        for (int i = 0; i < 4; ++i)
            #pragma unroll
            for (int j = 0; j < 4; ++j)
                acc[i][j] = __builtin_amdgcn_mfma_f32_16x16x32_bf16(
                                af[i], bf[j], acc[i][j], 0, 0, 0);
    }

    // ---- epilogue: +dec_proj, tanh, *v_w, reduce over this block's 128 cols
    float dpv[4], vwv[4];
    #pragma unroll
    for (int j = 0; j < 4; ++j) {
        int col = n0 + wc + j * 16 + ln;
        dpv[j] = dec_proj[b * Hdim + col];
        vwv[j] = v_w[col];
    }
    #pragma unroll
    for (int i = 0; i < 4; ++i) {
        #pragma unroll
        for (int reg = 0; reg < 4; ++reg) {
            float s = 0.0f;
            #pragma unroll
            for (int j = 0; j < 4; ++j) {
                float x = acc[i][j][reg] + dpv[j];
                s = fmaf(vwv[j], fast_tanh(x), s);
            }
            // sum across the 16 lanes of this quad (cols): xor low-4 lane bits
            s += __shfl_xor(s, 1, 64);
            s += __shfl_xor(s, 2, 64);
            s += __shfl_xor(s, 4, 64);
            s += __shfl_xor(s, 8, 64);
            if (ln == 0)
                redl[wr + i * 16 + quad * 4 + reg][w & 1] = s;
        }
    }
    __syncthreads();
    if (t < BM)
        part[(size_t)nblk * Mtot + row0 + t] = redl[t][0] + redl[t][1];
}

// ---------------- Kernel 3: sum partials + masked softmax -------------------
__global__ __launch_bounds__(256) void softmax_kernel(
    const float* __restrict__ part, const int* __restrict__ mask,
    float* __restrict__ out)
{
    __shared__ float sred[8];
    const int b = blockIdx.x;
    const int t = threadIdx.x;
    const int lane = t & 63;
    const int wid  = t >> 6;

    float x[8];
    float m = -1e30f;
    #pragma unroll
    for (int j = 0; j < 8; ++j) {
        int idx = b * Sdim + j * 256 + t;
        float v = part[idx] + part[Mtot + idx] + part[2 * Mtot + idx] + part[3 * Mtot + idx];
        if (mask[idx] == 0) v = -100000.0f;
        x[j] = v;
        m = fmaxf(m, v);
    }
    #pragma unroll
    for (int off = 32; off >= 1; off >>= 1)
        m = fmaxf(m, __shfl_xor(m, off, 64));
    if (lane == 0) sred[wid] = m;
    __syncthreads();
    m = fmaxf(fmaxf(sred[0], sred[1]), fmaxf(sred[2], sred[3]));

    float s = 0.0f;
    #pragma unroll
    for (int j = 0; j < 8; ++j) {
        float e = __expf(x[j] - m);
        x[j] = e;
        s += e;
    }
    #pragma unroll
    for (int off = 32; off >= 1; off >>= 1)
        s += __shfl_xor(s, off, 64);
    if (lane == 0) sred[4 + wid] = s;
    __syncthreads();
    s = sred[4] + sred[5] + sred[6] + sred[7];

    const float inv = 1.0f / s;
    #pragma unroll
    for (int j = 0; j < 8; ++j)
        out[b * Sdim + j * 256 + t] = x[j] * inv;
}

// ---------------- launch ----------------------------------------------------
extern "C" void kernel_launch(void* const* d_in, const int* in_sizes, int n_in,
                              void* d_out, int out_size, void* d_ws, size_t ws_size,
                              hipStream_t stream) {
    const float* dec  = (const float*)d_in[0];   // (B, H)
    const float* enc  = (const float*)d_in[1];   // (B, S, 2H)
    const int*   mask = (const int*)  d_in[2];   // (B, S)
    const float* W    = (const float*)d_in[3];   // (3H, H)
    const float* ba   = (const float*)d_in[4];   // (H,)
    const float* vw   = (const float*)d_in[5];   // (H,)
    float* out = (float*)d_out;                  // (B, S)

    // workspace layout (~2.2 MB)
    float* dec_proj = (float*)d_ws;                       // 32*512 f   = 64 KB
    short* Wb       = (short*)(dec_proj + Bdim * Hdim);   // 512*1024 s = 1 MB
    float* part     = (float*)(Wb + Hdim * Kdim);         // 4*65536 f  = 1 MB

    conv_W_kernel<<<512, 256, 0, stream>>>(W, Wb);
    dec_proj_kernel<<<dim3(Bdim, 4), 256, 0, stream>>>(dec, W, ba, dec_proj);
    scores_kernel<<<(Mtot / BM) * 4, 256, 0, stream>>>(enc, Wb, dec_proj, vw, part);
    softmax_kernel<<<Bdim, 256, 0, stream>>>(part, mask, out);
}